// Round 7
// baseline (103.174 us; speedup 1.0000x reference)
//
#include <hip/hip_runtime.h>
#include <math.h>

#define NPTS 131072
#define DDIM 64
#define KMIX 64
#define LOG_2PI 1.8378770664093453f

typedef __attribute__((ext_vector_type(8))) short short8;   // 8 bf16 (4 VGPRs)
typedef __attribute__((ext_vector_type(4))) float floatx4;  // 4 fp32 acc

// bf16 round-to-nearest-even
static __device__ __forceinline__ unsigned short f2bf(float f) {
    unsigned int u = __float_as_uint(f);
    unsigned int r = (u + 0x7fffu + ((u >> 16) & 1u)) >> 16;
    return (unsigned short)r;
}

// ---------------------------------------------------------------------------
// Fused prep: 64 blocks (k) x 64 threads (d). Every block computes C[k];
// blocks 0..15 additionally pack one MFMA A-fragment tile of W directly from
// mu/lv (no f32 intermediate).  W[k][i] = A[k][i] = -0.5*exp(-lv)  (i<64),
//                               W[k][64+d] = B[k][d] = mu*exp(-lv).
// Fragment (ktile t = b>>2, itile u = b&3): lane l holds
//   W[t*16 + (l&15)][u*32 + (l>>4)*8 + j],  packed lane-linear 16 B.
// C[k] = sum_d(-0.5*lv - 0.5*mu^2*exp(-lv)) - 0.5*D*log2pi + (lp[k]-LSE(lp))
// ---------------------------------------------------------------------------
__global__ void gmm_prep(const float* __restrict__ mu,
                         const float* __restrict__ lv,
                         const float* __restrict__ lp,
                         unsigned short* __restrict__ WhPack,  // [16][64][8]
                         float* __restrict__ C)                // [KMIX]
{
    const int k = blockIdx.x;
    const int d = threadIdx.x;

    // LSE over logpriors (lanes span K==64), redundantly per block
    float x = lp[d];
    float m = x;
    #pragma unroll
    for (int off = 32; off > 0; off >>= 1)
        m = fmaxf(m, __shfl_xor(m, off, 64));
    float s = expf(x - m);
    #pragma unroll
    for (int off = 32; off > 0; off >>= 1)
        s += __shfl_xor(s, off, 64);
    const float lse_lp = m + logf(s);

    const float l  = lv[k * DDIM + d];
    const float ev = expf(-l);
    const float mv = mu[k * DDIM + d];

    float c = -0.5f * l - 0.5f * mv * mv * ev;
    #pragma unroll
    for (int off = 32; off > 0; off >>= 1)
        c += __shfl_xor(c, off, 64);
    if (d == 0)
        C[k] = c + (lp[k] - lse_lp) - 0.5f * (float)DDIM * LOG_2PI;

    // pack (blocks 0..15 only)
    if (k < 16) {
        const int b     = k;
        const int krow  = (b >> 2) * 16 + (d & 15);
        const int ibase = (b & 3) * 32 + (d >> 4) * 8;
        short8 v;
        #pragma unroll
        for (int j = 0; j < 8; ++j) {
            const int i  = ibase + j;
            const int dd = i & 63;
            const float e = expf(-lv[krow * DDIM + dd]);
            const float w = (i < 64) ? (-0.5f * e) : (mu[krow * DDIM + dd] * e);
            v[j] = (short)f2bf(w);
        }
        *(short8*)(WhPack + (b * 64 + d) * 8) = v;
    }
}

// ---------------------------------------------------------------------------
// Main: block = 4 waves, 2 sequential units of 64 examples (128 n/block).
// Wave wid owns 16 columns per unit. Lane l builds B-fragments
// F = [x^2 (d 0..63); x (d 0..63)] in registers from its x-row (no LDS on
// the input path). A-fragments (Wh) + C hoisted once per block, amortized
// over 128 n. 16 MFMA per wave per unit. LSE over 64 k = in-thread 16-value
// reduce + shfl_xor(16,32). Epilogue per unit: block O-tile [64][68] in LDS,
// then linear float4 stores (256 B contiguous per k-row -> full 128 B lines,
// no read-for-ownership write amplification).
// ---------------------------------------------------------------------------
__global__ __launch_bounds__(256, 4)
void gmm_main(const float* __restrict__ xg,
              const unsigned short* __restrict__ WhPack,
              const float* __restrict__ C,
              float* __restrict__ out)
{
    __shared__ float O[KMIX * 68];   // 17.4 KB, padded row stride 68

    const int lane = threadIdx.x & 63;
    const int wid  = __builtin_amdgcn_readfirstlane(threadIdx.x >> 6);
    const int g    = lane >> 4;      // quad
    const int nn   = lane & 15;      // column within 16-wide tile

    const int bn0 = blockIdx.x * 128;       // block's n base (2 units x 64)
    const int col = wid * 16 + nn;          // 0..63 within a unit

    // hoisted Wh fragments (16 x 4 VGPR = 64 VGPR), L2-hot broadcast
    short8 wh[4][4];
    #pragma unroll
    for (int t = 0; t < 4; ++t)
        #pragma unroll
        for (int u = 0; u < 4; ++u)
            wh[t][u] = *(const short8*)(WhPack + ((t * 4 + u) * 64 + lane) * 8);

    // per-lane C values: rows t*16 + g*4 + r
    floatx4 cw[4];
    #pragma unroll
    for (int t = 0; t < 4; ++t)
        cw[t] = *(const floatx4*)(C + t * 16 + g * 4);

    #pragma unroll 1
    for (int unit = 0; unit < 2; ++unit) {
        const int un0 = bn0 + unit * 64;
        // x row for this lane's column: d in [g*8, g*8+8) and [32+g*8, ...)
        const float* __restrict__ xr = xg + (size_t)(un0 + col) * DDIM + g * 8;
        const float4 p0 = *(const float4*)(xr);
        const float4 p1 = *(const float4*)(xr + 4);
        const float4 p2 = *(const float4*)(xr + 32);
        const float4 p3 = *(const float4*)(xr + 36);
        const float ca[8] = {p0.x, p0.y, p0.z, p0.w, p1.x, p1.y, p1.z, p1.w};
        const float cb[8] = {p2.x, p2.y, p2.z, p2.w, p3.x, p3.y, p3.z, p3.w};

        // B-fragments: u=0: x^2 (d<32), u=1: x^2 (d>=32), u=2: x (d<32), u=3: x (d>=32)
        short8 bh[4];
        #pragma unroll
        for (int j = 0; j < 8; ++j) {
            bh[0][j] = (short)f2bf(ca[j] * ca[j]);
            bh[1][j] = (short)f2bf(cb[j] * cb[j]);
            bh[2][j] = (short)f2bf(ca[j]);
            bh[3][j] = (short)f2bf(cb[j]);
        }

        floatx4 acc[4];
        #pragma unroll
        for (int t = 0; t < 4; ++t) acc[t] = (floatx4){0.f, 0.f, 0.f, 0.f};

        #pragma unroll
        for (int u = 0; u < 4; ++u)
            #pragma unroll
            for (int t = 0; t < 4; ++t)
                acc[t] = __builtin_amdgcn_mfma_f32_16x16x32_bf16(wh[t][u], bh[u], acc[t], 0, 0, 0);

        // add C, LSE over the 64 k's of this column
        #pragma unroll
        for (int t = 0; t < 4; ++t)
            #pragma unroll
            for (int r = 0; r < 4; ++r)
                acc[t][r] += cw[t][r];

        float t8[8];
        #pragma unroll
        for (int i = 0; i < 8; ++i)
            t8[i] = fmaxf(acc[i >> 2][i & 3], acc[2 + (i >> 2)][i & 3]);
        #pragma unroll
        for (int i = 0; i < 4; ++i) t8[i] = fmaxf(t8[i], t8[i + 4]);
        float m = fmaxf(fmaxf(t8[0], t8[1]), fmaxf(t8[2], t8[3]));
        m = fmaxf(m, __shfl_xor(m, 16, 64));
        m = fmaxf(m, __shfl_xor(m, 32, 64));

        float s0 = 0.f, s1 = 0.f, s2 = 0.f, s3 = 0.f;
        #pragma unroll
        for (int t = 0; t < 4; ++t) {
            s0 += __expf(acc[t][0] - m);
            s1 += __expf(acc[t][1] - m);
            s2 += __expf(acc[t][2] - m);
            s3 += __expf(acc[t][3] - m);
        }
        float s = (s0 + s1) + (s2 + s3);
        s += __shfl_xor(s, 16, 64);
        s += __shfl_xor(s, 32, 64);
        const float lse = m + __logf(s);

        if (unit)
            __syncthreads();   // prior unit's O reads complete before overwrite

        // stage into block O-tile: row = t*16+g*4+r, col = wid*16+nn
        #pragma unroll
        for (int t = 0; t < 4; ++t)
            #pragma unroll
            for (int r = 0; r < 4; ++r)
                O[(t * 16 + g * 4 + r) * 68 + col] = acc[t][r] - lse;

        __syncthreads();

        // linear store: per instruction, 16 k-rows x 256 B contiguous
        #pragma unroll
        for (int rr = 0; rr < 4; ++rr) {
            const int row = rr * 16 + (threadIdx.x >> 4);
            const int c4  = (threadIdx.x & 15) * 4;
            const float4 v = *(const float4*)&O[row * 68 + c4];
            *(float4*)&out[(size_t)row * NPTS + un0 + c4] = v;
        }
    }
}

extern "C" void kernel_launch(void* const* d_in, const int* in_sizes, int n_in,
                              void* d_out, int out_size, void* d_ws, size_t ws_size,
                              hipStream_t stream) {
    const float* inputs    = (const float*)d_in[0];  // (N, D)
    const float* mu        = (const float*)d_in[1];  // (K, D)
    const float* logvars   = (const float*)d_in[2];  // (K, D)
    const float* logpriors = (const float*)d_in[3];  // (K,)

    float* out = (float*)d_out;                       // (K, N)

    // ws layout: WhPack 16 KB | C 256 B
    unsigned short* WhPack = (unsigned short*)d_ws;
    float* Cc = (float*)(WhPack + KMIX * 128);

    gmm_prep<<<KMIX, DDIM, 0, stream>>>(mu, logvars, logpriors, WhPack, Cc);
    gmm_main<<<NPTS / 128, 256, 0, stream>>>(inputs, WhPack, Cc, out);
}

// Round 8
// 93.443 us; speedup vs baseline: 1.1041x; 1.1041x over previous
//
#include <hip/hip_runtime.h>
#include <math.h>

#define NPTS 131072
#define DDIM 64
#define KMIX 64
#define LOG_2PI 1.8378770664093453f

typedef __attribute__((ext_vector_type(8))) short short8;   // 8 bf16 (4 VGPRs)
typedef __attribute__((ext_vector_type(4))) float floatx4;  // 4 fp32 acc

// bf16 round-to-nearest-even
static __device__ __forceinline__ unsigned short f2bf(float f) {
    unsigned int u = __float_as_uint(f);
    unsigned int r = (u + 0x7fffu + ((u >> 16) & 1u)) >> 16;
    return (unsigned short)r;
}

// ---------------------------------------------------------------------------
// Fused prep: 64 blocks (k) x 64 threads (d). Every block computes C[k];
// blocks 0..15 additionally pack one MFMA A-fragment tile of W (bf16)
// directly from mu/lv:  W[k][i<64] = -0.5*exp(-lv[k][i]),
//                       W[k][64+d] =  mu[k][d]*exp(-lv[k][d]).
// Fragment (ktile t = b>>2, itile u = b&3): lane l holds
//   W[t*16 + (l&15)][u*32 + (l>>4)*8 + j], packed lane-linear 16 B.
// C[k] = sum_d(-0.5*lv - 0.5*mu^2*exp(-lv)) - 0.5*D*log2pi + (lp[k]-LSE(lp))
// ---------------------------------------------------------------------------
__global__ void gmm_prep(const float* __restrict__ mu,
                         const float* __restrict__ lv,
                         const float* __restrict__ lp,
                         unsigned short* __restrict__ WhPack,  // [16][64][8]
                         float* __restrict__ C)                // [KMIX]
{
    const int k = blockIdx.x;
    const int d = threadIdx.x;

    // LSE over logpriors (lanes span K==64), redundantly per block
    float x = lp[d];
    float m = x;
    #pragma unroll
    for (int off = 32; off > 0; off >>= 1)
        m = fmaxf(m, __shfl_xor(m, off, 64));
    float s = expf(x - m);
    #pragma unroll
    for (int off = 32; off > 0; off >>= 1)
        s += __shfl_xor(s, off, 64);
    const float lse_lp = m + logf(s);

    const float l  = lv[k * DDIM + d];
    const float ev = expf(-l);
    const float mv = mu[k * DDIM + d];

    float c = -0.5f * l - 0.5f * mv * mv * ev;
    #pragma unroll
    for (int off = 32; off > 0; off >>= 1)
        c += __shfl_xor(c, off, 64);
    if (d == 0)
        C[k] = c + (lp[k] - lse_lp) - 0.5f * (float)DDIM * LOG_2PI;

    // pack (blocks 0..15 only)
    if (k < 16) {
        const int b     = k;
        const int krow  = (b >> 2) * 16 + (d & 15);
        const int ibase = (b & 3) * 32 + (d >> 4) * 8;
        short8 v;
        #pragma unroll
        for (int j = 0; j < 8; ++j) {
            const int i  = ibase + j;
            const int dd = i & 63;
            const float e = expf(-lv[krow * DDIM + dd]);
            const float w = (i < 64) ? (-0.5f * e) : (mu[krow * DDIM + dd] * e);
            v[j] = (short)f2bf(w);
        }
        *(short8*)(WhPack + (b * 64 + d) * 8) = v;
    }
}

// ---------------------------------------------------------------------------
// Main (R6 structure — best measured): wave = 16 examples; block = 4 waves
// = 64 n; 2048 blocks for max memory-level parallelism. Lane l builds
// B-fragments F = [x^2 (d 0..63); x (d 0..63)] in registers from its x-row
// (no LDS on the input path). A-fragments (Wh) hoisted in 64 VGPRs. 16 MFMA
// per wave. LSE over 64 k = in-thread 16-value reduce + shfl_xor(16,32).
// Epilogue: block O-tile [64][68] in LDS, then linear float4 stores — each
// instruction covers 256 B contiguous per k-row (full 128 B lines, no RFO
// write amplification).
// ---------------------------------------------------------------------------
__global__ __launch_bounds__(256, 4)
void gmm_main(const float* __restrict__ xg,
              const unsigned short* __restrict__ WhPack,
              const float* __restrict__ C,
              float* __restrict__ out)
{
    __shared__ float O[KMIX * 68];   // 17.4 KB, padded row stride 68

    const int lane = threadIdx.x & 63;
    const int wid  = __builtin_amdgcn_readfirstlane(threadIdx.x >> 6);
    const int g    = lane >> 4;      // quad
    const int nn   = lane & 15;      // column within 16-wide tile

    const int bn0 = blockIdx.x * 64;            // block's n base
    const int n   = bn0 + wid * 16 + nn;        // this lane's example column

    // x loads first (longest latency): row n, d in [g*8,g*8+8) and [32+g*8,..)
    const float* __restrict__ xr = xg + (size_t)n * DDIM + g * 8;
    const float4 p0 = *(const float4*)(xr);
    const float4 p1 = *(const float4*)(xr + 4);
    const float4 p2 = *(const float4*)(xr + 32);
    const float4 p3 = *(const float4*)(xr + 36);

    // hoisted Wh fragments (16 x 4 VGPR = 64 VGPR), L2-hot broadcast
    short8 wh[4][4];
    #pragma unroll
    for (int t = 0; t < 4; ++t)
        #pragma unroll
        for (int u = 0; u < 4; ++u)
            wh[t][u] = *(const short8*)(WhPack + ((t * 4 + u) * 64 + lane) * 8);

    // per-lane C values: rows t*16 + g*4 + r
    floatx4 cw[4];
    #pragma unroll
    for (int t = 0; t < 4; ++t)
        cw[t] = *(const floatx4*)(C + t * 16 + g * 4);

    const float ca[8] = {p0.x, p0.y, p0.z, p0.w, p1.x, p1.y, p1.z, p1.w};
    const float cb[8] = {p2.x, p2.y, p2.z, p2.w, p3.x, p3.y, p3.z, p3.w};

    // B-fragments: u=0: x^2 (d<32), u=1: x^2 (d>=32), u=2: x (d<32), u=3: x (d>=32)
    short8 bh[4];
    #pragma unroll
    for (int j = 0; j < 8; ++j) {
        bh[0][j] = (short)f2bf(ca[j] * ca[j]);
        bh[1][j] = (short)f2bf(cb[j] * cb[j]);
        bh[2][j] = (short)f2bf(ca[j]);
        bh[3][j] = (short)f2bf(cb[j]);
    }

    floatx4 acc[4];
    #pragma unroll
    for (int t = 0; t < 4; ++t) acc[t] = (floatx4){0.f, 0.f, 0.f, 0.f};

    #pragma unroll
    for (int u = 0; u < 4; ++u)
        #pragma unroll
        for (int t = 0; t < 4; ++t)
            acc[t] = __builtin_amdgcn_mfma_f32_16x16x32_bf16(wh[t][u], bh[u], acc[t], 0, 0, 0);

    // add C, then LSE over the 64 k's of column n
    #pragma unroll
    for (int t = 0; t < 4; ++t)
        #pragma unroll
        for (int r = 0; r < 4; ++r)
            acc[t][r] += cw[t][r];

    float t8[8];
    #pragma unroll
    for (int i = 0; i < 8; ++i)
        t8[i] = fmaxf(acc[i >> 2][i & 3], acc[2 + (i >> 2)][i & 3]);
    #pragma unroll
    for (int i = 0; i < 4; ++i) t8[i] = fmaxf(t8[i], t8[i + 4]);
    float m = fmaxf(fmaxf(t8[0], t8[1]), fmaxf(t8[2], t8[3]));
    m = fmaxf(m, __shfl_xor(m, 16, 64));
    m = fmaxf(m, __shfl_xor(m, 32, 64));

    float s0 = 0.f, s1 = 0.f, s2 = 0.f, s3 = 0.f;
    #pragma unroll
    for (int t = 0; t < 4; ++t) {
        s0 += __expf(acc[t][0] - m);
        s1 += __expf(acc[t][1] - m);
        s2 += __expf(acc[t][2] - m);
        s3 += __expf(acc[t][3] - m);
    }
    float s = (s0 + s1) + (s2 + s3);
    s += __shfl_xor(s, 16, 64);
    s += __shfl_xor(s, 32, 64);
    const float lse = m + __logf(s);

    // stage into block O-tile: row = t*16+g*4+r, col = wid*16+nn
    #pragma unroll
    for (int t = 0; t < 4; ++t)
        #pragma unroll
        for (int r = 0; r < 4; ++r)
            O[(t * 16 + g * 4 + r) * 68 + wid * 16 + nn] = acc[t][r] - lse;

    __syncthreads();

    // linear store: per instruction, 16 k-rows x 256 B contiguous (full lines)
    #pragma unroll
    for (int rr = 0; rr < 4; ++rr) {
        const int row = rr * 16 + (threadIdx.x >> 4);
        const int c4  = (threadIdx.x & 15) * 4;
        const float4 v = *(const float4*)&O[row * 68 + c4];
        *(float4*)&out[(size_t)row * NPTS + bn0 + c4] = v;
    }
}

extern "C" void kernel_launch(void* const* d_in, const int* in_sizes, int n_in,
                              void* d_out, int out_size, void* d_ws, size_t ws_size,
                              hipStream_t stream) {
    const float* inputs    = (const float*)d_in[0];  // (N, D)
    const float* mu        = (const float*)d_in[1];  // (K, D)
    const float* logvars   = (const float*)d_in[2];  // (K, D)
    const float* logpriors = (const float*)d_in[3];  // (K,)

    float* out = (float*)d_out;                       // (K, N)

    // ws layout: WhPack 16 KB | C 256 B
    unsigned short* WhPack = (unsigned short*)d_ws;
    float* Cc = (float*)(WhPack + KMIX * 128);

    gmm_prep<<<KMIX, DDIM, 0, stream>>>(mu, logvars, logpriors, WhPack, Cc);
    gmm_main<<<NPTS / 64, 256, 0, stream>>>(inputs, WhPack, Cc, out);
}